// Round 6
// baseline (2705.082 us; speedup 1.0000x reference)
//
#include <hip/hip_runtime.h>
#include <hip/hip_bf16.h>

// out[n,d] = b[d] + pk[n,d] + max_m ok[n,m,d]
//   pk = p @ Wp^T  (2048x1024,  K=1024)   -- small 128-tile kernel
//   ok = o @ Wo^T  (65536x1024, K=1024)   -- fused-convert 256^2 GEMM
// R6: LDS holds ONLY the A tile (2x32KB dbuf = 64KB -> 2 blocks/CU).
// B (2MB, L2-resident) is loaded global->reg per wave (bfr dbuf banks).
// A (f32) reg-staged coalesced -> cvt -> swizzled ds_write (2-deep aLe/aLo).
// One barrier per K-tile; single VMCNT(8) ledger point per tile.

#define NN 2048
#define MM 32
#define CC 1024

typedef __attribute__((ext_vector_type(8))) __bf16 bf16x8;
typedef __attribute__((ext_vector_type(4))) float f32x4;
typedef __attribute__((ext_vector_type(8))) unsigned short u16x8;
typedef __attribute__((ext_vector_type(4))) unsigned short u16x4;

__device__ inline unsigned short f2bf(float f) {
  union { __hip_bfloat16 h; unsigned short u; } v;
  v.h = __float2bfloat16(f);
  return v.u;
}

__device__ inline void gload_lds16(const void* g, void* l) {
  __builtin_amdgcn_global_load_lds(
      (const __attribute__((address_space(1))) void*)g,
      (__attribute__((address_space(3))) void*)l, 16, 0, 0);
}

// ---- convert person_features + split W into Wp/Wo (bf16) ----
__global__ void conv_pw(const float* __restrict__ p, const float* __restrict__ W,
                        unsigned short* __restrict__ pd,
                        unsigned short* __restrict__ wp,
                        unsigned short* __restrict__ wo) {
  const int PG = (NN * CC) / 8;
  const int WG = (CC * 2 * CC) / 8;
  int i = blockIdx.x * blockDim.x + threadIdx.x;
  int stride = gridDim.x * blockDim.x;
  for (; i < PG + WG; i += stride) {
    if (i < PG) {
      const float4* s = reinterpret_cast<const float4*>(p) + (size_t)i * 2;
      float4 a = s[0], b = s[1];
      u16x8 r;
      r[0] = f2bf(a.x); r[1] = f2bf(a.y); r[2] = f2bf(a.z); r[3] = f2bf(a.w);
      r[4] = f2bf(b.x); r[5] = f2bf(b.y); r[6] = f2bf(b.z); r[7] = f2bf(b.w);
      *reinterpret_cast<u16x8*>(pd + (size_t)i * 8) = r;
    } else {
      int f = i - PG;
      int e = f * 8;
      int d = e >> 11;
      int cc = e & 2047;
      const float4* s = reinterpret_cast<const float4*>(W) + (size_t)f * 2;
      float4 a = s[0], b = s[1];
      u16x8 r;
      r[0] = f2bf(a.x); r[1] = f2bf(a.y); r[2] = f2bf(a.z); r[3] = f2bf(a.w);
      r[4] = f2bf(b.x); r[5] = f2bf(b.y); r[6] = f2bf(b.z); r[7] = f2bf(b.w);
      unsigned short* o = (cc < CC) ? (wp + (size_t)d * CC + cc)
                                    : (wo + (size_t)d * CC + (cc - CC));
      *reinterpret_cast<u16x8*>(o) = r;
    }
  }
}

// ---- small 128x128 GEMM for pk+b ----
__global__ void gemm_pk(const unsigned short* __restrict__ A,
                        const unsigned short* __restrict__ B,
                        const float* __restrict__ bvec,
                        float* __restrict__ out) {
  __shared__ unsigned short As[128 * 64];
  __shared__ unsigned short Bs[128 * 64];

  int nb = gridDim.x;
  int chunk = nb >> 3;
  int obid = blockIdx.x;
  int vb = (obid & 7) * chunk + (obid >> 3);
  int bcol = vb & 7;
  int brow = vb >> 3;

  int tid = threadIdx.x;
  int l = tid & 63;
  int wid = tid >> 6;
  int wr = wid >> 1, wc = wid & 1;
  int lr = l & 15;
  int lk = (l >> 4) << 3;

  const unsigned short* gA = A + (size_t)brow * 128 * CC;
  const unsigned short* gB = B + (size_t)bcol * 128 * CC;

  f32x4 acc[4][4] = {};

  for (int kt = 0; kt < 16; ++kt) {
    int k0 = kt * 64;
#pragma unroll
    for (int j = 0; j < 4; ++j) {
      int f = (j * 256 + tid) * 8;
      int r = f >> 6;
      int c = f & 63;
      gload_lds16(gA + (size_t)r * CC + k0 + c, &As[f]);
      gload_lds16(gB + (size_t)r * CC + k0 + c, &Bs[f]);
    }
    __syncthreads();
#pragma unroll
    for (int kk = 0; kk < 2; ++kk) {
      bf16x8 af[4], bfr[4];
#pragma unroll
      for (int mi = 0; mi < 4; ++mi)
        af[mi] = *reinterpret_cast<const bf16x8*>(
            &As[(wr * 64 + mi * 16 + lr) * 64 + kk * 32 + lk]);
#pragma unroll
      for (int ni = 0; ni < 4; ++ni)
        bfr[ni] = *reinterpret_cast<const bf16x8*>(
            &Bs[(wc * 64 + ni * 16 + lr) * 64 + kk * 32 + lk]);
#pragma unroll
      for (int mi = 0; mi < 4; ++mi)
#pragma unroll
        for (int ni = 0; ni < 4; ++ni)
          acc[mi][ni] = __builtin_amdgcn_mfma_f32_16x16x32_bf16(
              af[mi], bfr[ni], acc[mi][ni], 0, 0, 0);
    }
    __syncthreads();
  }

#pragma unroll
  for (int mi = 0; mi < 4; ++mi) {
    int row = brow * 128 + wr * 64 + mi * 16 + (l >> 4) * 4;
#pragma unroll
    for (int ni = 0; ni < 4; ++ni) {
      int col = bcol * 128 + wc * 64 + ni * 16 + lr;
      float bb = bvec[col];
#pragma unroll
      for (int r = 0; r < 4; ++r)
        out[(size_t)(row + r) * CC + col] = acc[mi][ni][r] + bb;
    }
  }
}

// ==================== 256x256 main GEMM: A-only LDS, B in regs ==============
// LDS: A dbuf 2 x (256x64 bf16 = 32KB) at offsets 0 / 32768.
// Swizzle: LDS cell (row, chunk16B) holds global (row, chunk ^ (row&7)).
// Per tile t: VMCNT(8) [retires A(t+1)->regs + B(t)->regs], BLOAD B(t+1),
// ds_read A quadrants, cvt+write A(t+1) to other buf, issue A(t+3),
// 64 MFMA, LGKM0, BARRIER.  FIFO queue at tile start (steady):
// [A(t+1) 8][B(t) 8][A(t+2) 8] -> VMCNT(8) exact.

#define BARRIER                                      \
  do {                                               \
    asm volatile("" ::: "memory");                   \
    __builtin_amdgcn_s_barrier();                    \
    asm volatile("" ::: "memory");                   \
  } while (0)

#define LGKM0 asm volatile("s_waitcnt lgkmcnt(0)" ::: "memory")
#define VMCNT(n) asm volatile("s_waitcnt vmcnt(" #n ")" ::: "memory")

// coalesced A issue: instruction j covers rows 32j..32j+31, lane-contiguous.
#define ISSUE_A(aI, k0)                                                       \
  do {                                                                        \
    _Pragma("unroll") for (int j = 0; j < 8; ++j)                             \
        aI[j] = *reinterpret_cast<const float4*>(                             \
            gAf + (size_t)(j * 32 + arow0) * CC + (k0) + ac4 * 4);            \
  } while (0)

// convert + swizzled ds_write_b64 into A buffer at byte offset bofs
#define CVT_WRITE_A(aC, bofs)                                                 \
  do {                                                                        \
    _Pragma("unroll") for (int j = 0; j < 8; ++j) {                           \
      u16x4 r;                                                                \
      r[0] = f2bf(aC[j].x); r[1] = f2bf(aC[j].y);                             \
      r[2] = f2bf(aC[j].z); r[3] = f2bf(aC[j].w);                             \
      *reinterpret_cast<u16x4*>(lds + (bofs) +                                \
                                (j * 32 + arow0) * 128 + aswz) = r;           \
    }                                                                         \
  } while (0)

// B global->reg: wave quadrant (64 cols x 64 k) for K-tile kt
#define BLOAD(bf, kt)                                                         \
  do {                                                                        \
    _Pragma("unroll") for (int ni = 0; ni < 4; ++ni)                          \
      _Pragma("unroll") for (int kk = 0; kk < 2; ++kk)                        \
        bf[ni][kk] = *reinterpret_cast<const bf16x8*>(                        \
            gBw + (size_t)(ni * 16 + lr) * CC + (kt) * 64 + kk * 32 + g * 8); \
  } while (0)

#define DSREAD_A(bufo, mq, AF)                                                \
  do {                                                                        \
    _Pragma("unroll") for (int i = 0; i < 4; ++i) {                           \
      AF[i][0] = *(const bf16x8*)(lds + (bufo) + a_base0 + (mq) * 8192 + i * 2048); \
      AF[i][1] = *(const bf16x8*)(lds + (bufo) + a_base1 + (mq) * 8192 + i * 2048); \
    }                                                                         \
  } while (0)

#define MFMA16(AF, mq, nq, BF)                                                \
  do {                                                                        \
    __builtin_amdgcn_s_setprio(1);                                            \
    _Pragma("unroll") for (int i = 0; i < 4; ++i)                             \
        _Pragma("unroll") for (int j = 0; j < 2; ++j) {                       \
      acc[(mq) * 4 + i][(nq) * 2 + j] = __builtin_amdgcn_mfma_f32_16x16x32_bf16( \
          AF[i][0], BF[(nq) * 2 + j][0], acc[(mq) * 4 + i][(nq) * 2 + j], 0, 0, 0); \
      acc[(mq) * 4 + i][(nq) * 2 + j] = __builtin_amdgcn_mfma_f32_16x16x32_bf16( \
          AF[i][1], BF[(nq) * 2 + j][1], acc[(mq) * 4 + i][(nq) * 2 + j], 0, 0, 0); \
    }                                                                         \
    __builtin_amdgcn_s_setprio(0);                                            \
  } while (0)

// One K-tile t: read A from bufo, write A(t+1) into bufn; B cur bank BC,
// next bank BN; ALC = aL bank holding A(t+1) (parity (t+1)&1).
#define TILE(t, bufo, bufn, BC, BN, ALC)                                      \
  do {                                                                        \
    if ((t) <= 13) { VMCNT(8); } else { VMCNT(0); }                           \
    if ((t) + 1 < 16) BLOAD(BN, (t) + 1);                                     \
    DSREAD_A(bufo, 0, af);                                                    \
    DSREAD_A(bufo, 1, af2);                                                   \
    if ((t) + 1 < 16) CVT_WRITE_A(ALC, bufn);                                 \
    if ((t) + 3 < 16) ISSUE_A(ALC, ((t) + 3) * 64);                           \
    MFMA16(af, 0, 0, BC);                                                     \
    MFMA16(af, 0, 1, BC);                                                     \
    MFMA16(af2, 1, 0, BC);                                                    \
    MFMA16(af2, 1, 1, BC);                                                    \
    LGKM0;                                                                    \
    BARRIER;                                                                  \
  } while (0)

__global__ __launch_bounds__(512, 4) void gemm_fused(
    const float* __restrict__ A,
    const unsigned short* __restrict__ B,
    const float* __restrict__ pkb,
    float* __restrict__ out) {
  __shared__ char lds[65536];

  int obid = blockIdx.x;                    // 1024 blocks
  int vb = (obid & 7) * 128 + (obid >> 3);  // XCD-contiguous (1024 % 8 == 0)
  int bcol = vb & 3;                        // 4 col tiles
  int brow = vb >> 2;                       // 256 row tiles

  int tid = threadIdx.x;
  int l = tid & 63;
  int wid = tid >> 6;
  int wr = wid >> 2;   // 0..1
  int wc = wid & 3;    // 0..3
  int lr = l & 15;
  int g = l >> 4;      // 0..3

  const float* gAf = A + (size_t)brow * 256 * CC;
  const unsigned short* gBw = B + (size_t)(bcol * 256 + wc * 64) * CC;

  // A reg-staging addressing (coalesced): instr j -> row j*32+arow0, 16B col ac4
  int arow0 = tid >> 4;                      // 0..31
  int ac4 = tid & 15;                        // 16B column index (f32)
  int aswz = (((ac4 >> 1) ^ (arow0 & 7)) * 16) + (ac4 & 1) * 8;

  // ds_read byte offsets: row R, chunk (kk*4+g)^(R&7); R&7 == lr&7
  int axor = lr & 7;
  int a_base0 = (wr * 128 + lr) * 128 + ((g ^ axor) * 16);
  int a_base1 = (wr * 128 + lr) * 128 + (((4 + g) ^ axor) * 16);

  f32x4 acc[8][4] = {};
  bf16x8 af[4][2], af2[4][2];
  bf16x8 bfrE[4][2], bfrO[4][2];
  float4 aLe[8], aLo[8];

  // prologue: order A(0), A(1), B(0); retire A(0) [VMCNT(16)]; write A(0)
  // to buf0; issue A(2). Queue at loop entry: [A(1) 8][B(0) 8][A(2) 8].
  ISSUE_A(aLe, 0);
  ISSUE_A(aLo, 64);
  BLOAD(bfrE, 0);
  VMCNT(16);
  CVT_WRITE_A(aLe, 0);
  ISSUE_A(aLe, 128);
  LGKM0; BARRIER;

#pragma unroll 1
  for (int tt = 0; tt < 16; tt += 2) {
    TILE(tt,     0,     32768, bfrE, bfrO, aLo);
    TILE(tt + 1, 32768, 0,     bfrO, bfrE, aLe);
  }

  // fused epilogue: max over 32 consecutive A-rows per n, + pkb
  int colb = bcol * 256 + wc * 64;
#pragma unroll
  for (int a = 0; a < 4; ++a) {
    int n = brow * 8 + wr * 4 + a;
#pragma unroll
    for (int ni = 0; ni < 4; ++ni) {
      float v = -3.402823466e38f;
#pragma unroll
      for (int mi = 2 * a; mi < 2 * a + 2; ++mi)
#pragma unroll
        for (int r = 0; r < 4; ++r) v = fmaxf(v, acc[mi][ni][r]);
      v = fmaxf(v, __shfl_xor(v, 16));
      v = fmaxf(v, __shfl_xor(v, 32));
      if (l < 16) {
        int col = colb + ni * 16 + l;
        out[(size_t)n * CC + col] = v + pkb[(size_t)n * CC + col];
      }
    }
  }
}

extern "C" void kernel_launch(void* const* d_in, const int* in_sizes, int n_in,
                              void* d_out, int out_size, void* d_ws, size_t ws_size,
                              hipStream_t stream) {
  const float* p = (const float*)d_in[0];   // (N, C, 1, 1)
  const float* o = (const float*)d_in[1];   // (N, M, C, 1, 1)
  const float* W = (const float*)d_in[5];   // (C, 2C)
  const float* b = (const float*)d_in[6];   // (C,)
  float* out = (float*)d_out;               // (N, C, 1, 1)

  char* ws = (char*)d_ws;
  unsigned short* p_bf  = (unsigned short*)ws;                 // 4 MB
  unsigned short* wp_bf = (unsigned short*)(ws + 4194304);     // 2 MB
  unsigned short* wo_bf = (unsigned short*)(ws + 6291456);     // 2 MB
  float*          pkb   = (float*)(ws + 8388608);              // 8 MB

  conv_pw<<<512, 256, 0, stream>>>(p, W, p_bf, wp_bf, wo_bf);
  gemm_pk<<<128, 256, 0, stream>>>(p_bf, wp_bf, b, pkb);
  gemm_fused<<<1024, 512, 0, stream>>>(o, wo_bf, pkb, out);
}

// Round 8
// 203.424 us; speedup vs baseline: 13.2977x; 13.2977x over previous
//
#include <hip/hip_runtime.h>
#include <hip/hip_bf16.h>

// out[n,d] = b[d] + pk[n,d] + max_m ok[n,m,d]
//   pk = p @ Wp^T  (2048x1024,  K=1024)   -- small 128-tile kernel
//   ok = o @ Wo^T  (65536x1024, K=1024)   -- fused-convert 256^2 4-phase GEMM
// R8 = R7 with the ph3 B-stage buffer-index fix: B(t+2) -> buf (t&1)
// (R7 wrote buf ((t+1)&1), shifting the B sequence by one tile).

#define NN 2048
#define MM 32
#define CC 1024

typedef __attribute__((ext_vector_type(8))) __bf16 bf16x8;
typedef __attribute__((ext_vector_type(4))) float f32x4;
typedef __attribute__((ext_vector_type(8))) unsigned short u16x8;
typedef __attribute__((ext_vector_type(4))) unsigned short u16x4;

__device__ inline unsigned short f2bf(float f) {
  union { __hip_bfloat16 h; unsigned short u; } v;
  v.h = __float2bfloat16(f);
  return v.u;
}

__device__ inline void gload_lds16(const void* g, void* l) {
  __builtin_amdgcn_global_load_lds(
      (const __attribute__((address_space(1))) void*)g,
      (__attribute__((address_space(3))) void*)l, 16, 0, 0);
}

// ---- convert person_features + split W into Wp/Wo (bf16) ----
__global__ void conv_pw(const float* __restrict__ p, const float* __restrict__ W,
                        unsigned short* __restrict__ pd,
                        unsigned short* __restrict__ wp,
                        unsigned short* __restrict__ wo) {
  const int PG = (NN * CC) / 8;
  const int WG = (CC * 2 * CC) / 8;
  int i = blockIdx.x * blockDim.x + threadIdx.x;
  int stride = gridDim.x * blockDim.x;
  for (; i < PG + WG; i += stride) {
    if (i < PG) {
      const float4* s = reinterpret_cast<const float4*>(p) + (size_t)i * 2;
      float4 a = s[0], b = s[1];
      u16x8 r;
      r[0] = f2bf(a.x); r[1] = f2bf(a.y); r[2] = f2bf(a.z); r[3] = f2bf(a.w);
      r[4] = f2bf(b.x); r[5] = f2bf(b.y); r[6] = f2bf(b.z); r[7] = f2bf(b.w);
      *reinterpret_cast<u16x8*>(pd + (size_t)i * 8) = r;
    } else {
      int f = i - PG;
      int e = f * 8;
      int d = e >> 11;
      int cc = e & 2047;
      const float4* s = reinterpret_cast<const float4*>(W) + (size_t)f * 2;
      float4 a = s[0], b = s[1];
      u16x8 r;
      r[0] = f2bf(a.x); r[1] = f2bf(a.y); r[2] = f2bf(a.z); r[3] = f2bf(a.w);
      r[4] = f2bf(b.x); r[5] = f2bf(b.y); r[6] = f2bf(b.z); r[7] = f2bf(b.w);
      unsigned short* o = (cc < CC) ? (wp + (size_t)d * CC + cc)
                                    : (wo + (size_t)d * CC + (cc - CC));
      *reinterpret_cast<u16x8*>(o) = r;
    }
  }
}

// ---- small 128x128 GEMM for pk+b ----
__global__ void gemm_pk(const unsigned short* __restrict__ A,
                        const unsigned short* __restrict__ B,
                        const float* __restrict__ bvec,
                        float* __restrict__ out) {
  __shared__ unsigned short As[128 * 64];
  __shared__ unsigned short Bs[128 * 64];

  int nb = gridDim.x;
  int chunk = nb >> 3;
  int obid = blockIdx.x;
  int vb = (obid & 7) * chunk + (obid >> 3);
  int bcol = vb & 7;
  int brow = vb >> 3;

  int tid = threadIdx.x;
  int l = tid & 63;
  int wid = tid >> 6;
  int wr = wid >> 1, wc = wid & 1;
  int lr = l & 15;
  int lk = (l >> 4) << 3;

  const unsigned short* gA = A + (size_t)brow * 128 * CC;
  const unsigned short* gB = B + (size_t)bcol * 128 * CC;

  f32x4 acc[4][4] = {};

  for (int kt = 0; kt < 16; ++kt) {
    int k0 = kt * 64;
#pragma unroll
    for (int j = 0; j < 4; ++j) {
      int f = (j * 256 + tid) * 8;
      int r = f >> 6;
      int c = f & 63;
      gload_lds16(gA + (size_t)r * CC + k0 + c, &As[f]);
      gload_lds16(gB + (size_t)r * CC + k0 + c, &Bs[f]);
    }
    __syncthreads();
#pragma unroll
    for (int kk = 0; kk < 2; ++kk) {
      bf16x8 af[4], bfr[4];
#pragma unroll
      for (int mi = 0; mi < 4; ++mi)
        af[mi] = *reinterpret_cast<const bf16x8*>(
            &As[(wr * 64 + mi * 16 + lr) * 64 + kk * 32 + lk]);
#pragma unroll
      for (int ni = 0; ni < 4; ++ni)
        bfr[ni] = *reinterpret_cast<const bf16x8*>(
            &Bs[(wc * 64 + ni * 16 + lr) * 64 + kk * 32 + lk]);
#pragma unroll
      for (int mi = 0; mi < 4; ++mi)
#pragma unroll
        for (int ni = 0; ni < 4; ++ni)
          acc[mi][ni] = __builtin_amdgcn_mfma_f32_16x16x32_bf16(
              af[mi], bfr[ni], acc[mi][ni], 0, 0, 0);
    }
    __syncthreads();
  }

#pragma unroll
  for (int mi = 0; mi < 4; ++mi) {
    int row = brow * 128 + wr * 64 + mi * 16 + (l >> 4) * 4;
#pragma unroll
    for (int ni = 0; ni < 4; ++ni) {
      int col = bcol * 128 + wc * 64 + ni * 16 + lr;
      float bb = bvec[col];
#pragma unroll
      for (int r = 0; r < 4; ++r)
        out[(size_t)(row + r) * CC + col] = acc[mi][ni][r] + bb;
    }
  }
}

// ==================== 256x256 4-phase main GEMM, fused A-convert ============
// LDS: 2 bufs x (A 32KB @ +0, B 32KB @ +32768); buf k at k*65536. 128KB total.
// Swizzle: LDS cell (row, chunk16B) holds global (row, chunk ^ (row&7)).
// vmcnt FIFO ledger (A issue=8 @ph2, B stage=4 @ph3):
//   ph2: vmcnt(4)  retires A(t+1)  [leaves B(t+1)4]
//   ph4: vmcnt(12) retires B(t+1)  [leaves A(t+2)8 + B(t+2)4]
//   t=14: ph2 vmcnt(4), ph4 vmcnt(0).

#define BARRIER                                      \
  do {                                               \
    asm volatile("" ::: "memory");                   \
    __builtin_amdgcn_s_barrier();                    \
    asm volatile("" ::: "memory");                   \
  } while (0)

#define LGKM0 asm volatile("s_waitcnt lgkmcnt(0)" ::: "memory")
#define VMCNT(n) asm volatile("s_waitcnt vmcnt(" #n ")" ::: "memory")

#define STAGE(gsrc, bufidx, isB, h, k0)                                       \
  do {                                                                        \
    _Pragma("unroll") for (int ii = 0; ii < 2; ++ii)                          \
        gload_lds16(gsrc + (size_t)((h) * 128 + ii * 64 + rr) * CC + (k0) + sc, \
                    lds + (bufidx) * 65536 + (isB) * 32768 + (h) * 16384 +    \
                        ii * 8192 + tid * 16);                                \
  } while (0)

// coalesced A issue: instruction j covers rows 32j..32j+31, lane-contiguous.
#define ISSUE_A(aI, k0)                                                       \
  do {                                                                        \
    _Pragma("unroll") for (int j = 0; j < 8; ++j)                             \
        aI[j] = *reinterpret_cast<const float4*>(                             \
            gAf + (size_t)(j * 32 + arow0) * CC + (k0) + ac4 * 4);            \
  } while (0)

// convert + swizzled ds_write_b64 into buffer bufidx's A region
#define CVT_WRITE_A(aC, bufidx)                                               \
  do {                                                                        \
    _Pragma("unroll") for (int j = 0; j < 8; ++j) {                           \
      u16x4 r;                                                                \
      r[0] = f2bf(aC[j].x); r[1] = f2bf(aC[j].y);                             \
      r[2] = f2bf(aC[j].z); r[3] = f2bf(aC[j].w);                             \
      *reinterpret_cast<u16x4*>(lds + (bufidx) * 65536 +                      \
                                (j * 32 + arow0) * 128 + aswz) = r;           \
    }                                                                         \
  } while (0)

#define DSREAD_A(bufo, mq, AF)                                                \
  do {                                                                        \
    _Pragma("unroll") for (int i = 0; i < 4; ++i) {                           \
      AF[i][0] = *(const bf16x8*)(lds + (bufo) + a_base0 + (mq) * 8192 + i * 2048); \
      AF[i][1] = *(const bf16x8*)(lds + (bufo) + a_base1 + (mq) * 8192 + i * 2048); \
    }                                                                         \
  } while (0)

#define DSREAD_B(bufo, nq)                                                    \
  do {                                                                        \
    _Pragma("unroll") for (int j = 0; j < 2; ++j) {                           \
      bfr[(nq) * 2 + j][0] =                                                  \
          *(const bf16x8*)(lds + (bufo) + b_base0 + ((nq) * 2 + j) * 2048);   \
      bfr[(nq) * 2 + j][1] =                                                  \
          *(const bf16x8*)(lds + (bufo) + b_base1 + ((nq) * 2 + j) * 2048);   \
    }                                                                         \
  } while (0)

#define MFMA16(AF, mq, nq)                                                    \
  do {                                                                        \
    __builtin_amdgcn_s_setprio(1);                                            \
    _Pragma("unroll") for (int i = 0; i < 4; ++i)                             \
        _Pragma("unroll") for (int j = 0; j < 2; ++j) {                       \
      acc[(mq) * 4 + i][(nq) * 2 + j] = __builtin_amdgcn_mfma_f32_16x16x32_bf16( \
          AF[i][0], bfr[(nq) * 2 + j][0], acc[(mq) * 4 + i][(nq) * 2 + j], 0, 0, 0); \
      acc[(mq) * 4 + i][(nq) * 2 + j] = __builtin_amdgcn_mfma_f32_16x16x32_bf16( \
          AF[i][1], bfr[(nq) * 2 + j][1], acc[(mq) * 4 + i][(nq) * 2 + j], 0, 0, 0); \
    }                                                                         \
    __builtin_amdgcn_s_setprio(0);                                            \
  } while (0)

// One K-tile t: reads from bufo=(t&1); A(t+1) cvt-written to buf((t+1)&1)
// at ph2; B(t+2) staged to buf(t&1) at ph3 (same region this tile already
// finished reading -- safe: all waves' B reads completed before the
// ph2-end barrier, same argument as R2).
#define TILE(t, bufo)                                                         \
  do {                                                                        \
    DSREAD_A(bufo, 0, af);                                                    \
    DSREAD_B(bufo, 0);                                                        \
    BARRIER; LGKM0;                                                           \
    MFMA16(af, 0, 0);                                                         \
    BARRIER;                                                                  \
    DSREAD_B(bufo, 1);                                                        \
    if ((t) + 1 < 16) {                                                       \
      VMCNT(4);                                                               \
      CVT_WRITE_A(aL, (((t) + 1) & 1));                                       \
      if ((t) + 2 < 16) ISSUE_A(aL, ((t) + 2) * 64);                          \
    }                                                                         \
    BARRIER; LGKM0;                                                           \
    MFMA16(af, 0, 1);                                                         \
    BARRIER;                                                                  \
    DSREAD_A(bufo, 1, af2);                                                   \
    if ((t) + 2 < 16) {                                                       \
      STAGE(gB, ((t) & 1), 1, 0, ((t) + 2) * 64);                             \
      STAGE(gB, ((t) & 1), 1, 1, ((t) + 2) * 64);                             \
    }                                                                         \
    BARRIER; LGKM0;                                                           \
    MFMA16(af2, 1, 0);                                                        \
    BARRIER;                                                                  \
    MFMA16(af2, 1, 1);                                                        \
    if ((t) <= 13) { VMCNT(12); }                                             \
    else if ((t) == 14) { VMCNT(0); }                                         \
    BARRIER;                                                                  \
  } while (0)

__global__ __launch_bounds__(512, 2) void gemm_fused(
    const float* __restrict__ A,
    const unsigned short* __restrict__ B,
    const float* __restrict__ pkb,
    float* __restrict__ out) {
  __shared__ char lds[131072];

  int obid = blockIdx.x;                    // 1024 blocks
  int vb = (obid & 7) * 128 + (obid >> 3);  // XCD-contiguous (1024 % 8 == 0)
  int bcol = vb & 3;                        // 4 col tiles
  int brow = vb >> 2;                       // 256 row tiles

  int tid = threadIdx.x;
  int l = tid & 63;
  int wid = tid >> 6;
  int wr = wid >> 2;   // 0..1
  int wc = wid & 3;    // 0..3
  int lr = l & 15;
  int g = l >> 4;      // 0..3

  const float* gAf = A + (size_t)brow * 256 * CC;
  const unsigned short* gB = B + (size_t)bcol * 256 * CC;

  // B staging addressing (linear LDS dest, inverse-swizzled global source)
  int rr = tid >> 3;
  int sc = ((tid & 7) ^ (rr & 7)) * 8;

  // A reg-staging addressing (coalesced): instr j -> row j*32+arow0, 16B col ac4
  int arow0 = tid >> 4;                      // 0..31
  int ac4 = tid & 15;                        // 16B column index (f32)
  int aswz = (((ac4 >> 1) ^ (arow0 & 7)) * 16) + (ac4 & 1) * 8;

  // ds_read byte offsets: row R, chunk (kk*4+g)^(R&7); R&7 == lr&7
  int axor = lr & 7;
  int a_base0 = (wr * 128 + lr) * 128 + ((g ^ axor) * 16);
  int a_base1 = (wr * 128 + lr) * 128 + (((4 + g) ^ axor) * 16);
  int b_base0 = 32768 + (wc * 64 + lr) * 128 + ((g ^ axor) * 16);
  int b_base1 = 32768 + (wc * 64 + lr) * 128 + (((4 + g) ^ axor) * 16);

  f32x4 acc[8][4] = {};
  bf16x8 af[4][2], af2[4][2];
  bf16x8 bfr[4][2];
  float4 aL[8];

  // prologue (FIFO keeps A older than residual B):
  //   A0[8]; B0[4]; vmcnt(4) retires A0; cvt+write A0 -> buf0;
  //   A1[8]; B1[4]; vmcnt(12) retires B0. Queue: [A1 8, B1 4].
  ISSUE_A(aL, 0);
  STAGE(gB, 0, 1, 0, 0);
  STAGE(gB, 0, 1, 1, 0);
  VMCNT(4);
  CVT_WRITE_A(aL, 0);
  ISSUE_A(aL, 64);
  STAGE(gB, 1, 1, 0, 64);
  STAGE(gB, 1, 1, 1, 64);
  VMCNT(12);
  LGKM0; BARRIER;

#pragma unroll 1
  for (int tt = 0; tt < 16; tt += 2) {
    TILE(tt, 0);
    TILE(tt + 1, 65536);
  }

  // fused epilogue: max over 32 consecutive A-rows per n, + pkb
  int colb = bcol * 256 + wc * 64;
#pragma unroll
  for (int a = 0; a < 4; ++a) {
    int n = brow * 8 + wr * 4 + a;
#pragma unroll
    for (int ni = 0; ni < 4; ++ni) {
      float v = -3.402823466e38f;
#pragma unroll
      for (int mi = 2 * a; mi < 2 * a + 2; ++mi)
#pragma unroll
        for (int r = 0; r < 4; ++r) v = fmaxf(v, acc[mi][ni][r]);
      v = fmaxf(v, __shfl_xor(v, 16));
      v = fmaxf(v, __shfl_xor(v, 32));
      if (l < 16) {
        int col = colb + ni * 16 + l;
        out[(size_t)n * CC + col] = v + pkb[(size_t)n * CC + col];
      }
    }
  }
}

extern "C" void kernel_launch(void* const* d_in, const int* in_sizes, int n_in,
                              void* d_out, int out_size, void* d_ws, size_t ws_size,
                              hipStream_t stream) {
  const float* p = (const float*)d_in[0];   // (N, C, 1, 1)
  const float* o = (const float*)d_in[1];   // (N, M, C, 1, 1)
  const float* W = (const float*)d_in[5];   // (C, 2C)
  const float* b = (const float*)d_in[6];   // (C,)
  float* out = (float*)d_out;               // (N, C, 1, 1)

  char* ws = (char*)d_ws;
  unsigned short* p_bf  = (unsigned short*)ws;                 // 4 MB
  unsigned short* wp_bf = (unsigned short*)(ws + 4194304);     // 2 MB
  unsigned short* wo_bf = (unsigned short*)(ws + 6291456);     // 2 MB
  float*          pkb   = (float*)(ws + 8388608);              // 8 MB

  conv_pw<<<512, 256, 0, stream>>>(p, W, p_bf, wp_bf, wo_bf);
  gemm_pk<<<128, 256, 0, stream>>>(p_bf, wp_bf, b, pkb);
  gemm_fused<<<1024, 512, 0, stream>>>(o, wo_bf, pkb, out);
}